// Round 2
// baseline (611.524 us; speedup 1.0000x reference)
//
#include <hip/hip_runtime.h>
#include <stdint.h>

#define N_NODES 50000
#define E_EDGES 300000
#define C_CH    256
#define H_HEADS 8

typedef unsigned short u16;
typedef unsigned int   u32;

typedef __attribute__((ext_vector_type(8))) short  v8s;   // 8 bf16 (MFMA A/B frag)
typedef __attribute__((ext_vector_type(4))) float  v4f;   // MFMA C/D frag

__device__ __forceinline__ float bf2f(u16 v) {
    union { u32 u; float f; } x; x.u = ((u32)v) << 16; return x.f;
}
__device__ __forceinline__ u16 f2bf(float f) {
    union { float f; u32 u; } x; x.f = f;
    u32 r = (x.u + 0x7FFFu + ((x.u >> 16) & 1u)) >> 16;
    return (u16)r;
}

// ---------------------------------------------------------------------------
// fp32 -> bf16 convert (n multiple of 4)
// ---------------------------------------------------------------------------
__global__ __launch_bounds__(256) void cvt_k(
    const float* __restrict__ in, u16* __restrict__ out, int n)
{
    int i = (blockIdx.x * 256 + threadIdx.x) * 4;
    if (i >= n) return;
    float4 v = *(const float4*)(in + i);
    ushort4 o;
    o.x = f2bf(v.x); o.y = f2bf(v.y); o.z = f2bf(v.z); o.w = f2bf(v.w);
    *(ushort4*)(out + i) = o;
}

// ---------------------------------------------------------------------------
// GEMM: OUT[M,256] = X[M,256] @ W[256,256]^T + bias   (bf16 in, fp32 acc,
// bf16 out). 64x64 tile per block (4 waves), BK=32, mfma_f32_16x16x32_bf16.
// ---------------------------------------------------------------------------
#define LDT 40   // LDS row stride in bf16 elems (80 B: 16B-aligned, 2-way max)

__global__ __launch_bounds__(256) void gemm_bt(
    const u16* __restrict__ X, const u16* __restrict__ W,
    const float* __restrict__ bias, u16* __restrict__ OUT, int M)
{
    __shared__ u16 As[64 * LDT];
    __shared__ u16 Bs[64 * LDT];
    const int t    = threadIdx.x;
    const int m0   = blockIdx.x * 64;
    const int n0   = blockIdx.y * 64;
    const int lane = t & 63, wave = t >> 6;
    const int quad = lane >> 4, l15 = lane & 15;

    v4f acc[4];
#pragma unroll
    for (int i = 0; i < 4; i++) acc[i] = (v4f)(0.0f);

    const int lrow = t >> 2;         // 0..63
    const int lseg = (t & 3) * 8;    // 0,8,16,24

    for (int k0 = 0; k0 < 256; k0 += 32) {
        int gr = m0 + lrow;
        uint4 av = make_uint4(0u, 0u, 0u, 0u);
        if (gr < M) av = *(const uint4*)(X + (size_t)gr * 256 + k0 + lseg);
        *(uint4*)(As + lrow * LDT + lseg) = av;
        uint4 bv = *(const uint4*)(W + (size_t)(n0 + lrow) * 256 + k0 + lseg);
        *(uint4*)(Bs + lrow * LDT + lseg) = bv;
        __syncthreads();

        v8s a = *(const v8s*)(As + (wave * 16 + l15) * LDT + quad * 8);
#pragma unroll
        for (int nt = 0; nt < 4; nt++) {
            v8s b = *(const v8s*)(Bs + (nt * 16 + l15) * LDT + quad * 8);
            acc[nt] = __builtin_amdgcn_mfma_f32_16x16x32_bf16(a, b, acc[nt], 0, 0, 0);
        }
        __syncthreads();
    }

#pragma unroll
    for (int nt = 0; nt < 4; nt++) {
        int n = n0 + nt * 16 + l15;
        float bi = bias[n];
#pragma unroll
        for (int r = 0; r < 4; r++) {
            int m = m0 + wave * 16 + quad * 4 + r;   // C/D: row=quad*4+reg, col=lane&15
            if (m < M) OUT[(size_t)m * 256 + n] = f2bf(acc[nt][r] + bi);
        }
    }
}

// ---------------------------------------------------------------------------
// Edge prep: dst histogram (CSR sizes) + anchor-subgraph adjacency bitmask
// inmask[d][w] bit s  <=>  exists edge (src=s<256 -> dst=d)
// ---------------------------------------------------------------------------
__global__ __launch_bounds__(256) void edge_prep(
    const int* __restrict__ src, const int* __restrict__ dst,
    u32* __restrict__ cnt_dst, u32* __restrict__ inmask)
{
    int e = blockIdx.x * 256 + threadIdx.x;
    if (e >= E_EDGES) return;
    int s = src[e], d = dst[e];
    atomicAdd(&cnt_dst[d], 1u);
    if (s < 256) atomicOr(&inmask[d * 8 + (s >> 5)], 1u << (s & 31));
}

// ---------------------------------------------------------------------------
// SPD: 3-level exact-length reachability on the 256-anchor subgraph.
// F_k[i] (256-bit) = anchors m with a walk m->i of length exactly k.
// T[i*256+m] = first k in {1,2,3} with bit set, else 4.  spd[e]=T[src][dst].
// ---------------------------------------------------------------------------
__global__ __launch_bounds__(256) void spd_levels(
    const u32* __restrict__ inmask, unsigned char* __restrict__ T)
{
    __shared__ u32 F1[256][8], F2[256][8], F3[256][8];
    int i = threadIdx.x;
#pragma unroll
    for (int w = 0; w < 8; w++) { F1[i][w] = inmask[i * 8 + w]; F2[i][w] = 0; F3[i][w] = 0; }
    __syncthreads();
    for (int w = 0; w < 8; w++) {
        u32 m = F1[i][w];
        while (m) {
            int b = __ffs(m) - 1; m &= m - 1;
            int s = w * 32 + b;
#pragma unroll
            for (int j = 0; j < 8; j++) F2[i][j] |= F1[s][j];
        }
    }
    __syncthreads();
    for (int w = 0; w < 8; w++) {
        u32 m = F1[i][w];
        while (m) {
            int b = __ffs(m) - 1; m &= m - 1;
            int s = w * 32 + b;
#pragma unroll
            for (int j = 0; j < 8; j++) F3[i][j] |= F2[s][j];
        }
    }
    __syncthreads();
    for (int w = 0; w < 8; w++) {
        u32 f1 = F1[i][w], f2 = F2[i][w], f3 = F3[i][w];
#pragma unroll
        for (int g = 0; g < 8; g++) {
            u32 word = 0;
#pragma unroll
            for (int b = 0; b < 4; b++) {
                int bit = g * 4 + b;
                u32 k = ((f1 >> bit) & 1u) ? 1u : ((f2 >> bit) & 1u) ? 2u
                       : ((f3 >> bit) & 1u) ? 3u : 4u;
                word |= k << (8 * b);
            }
            *(u32*)(T + i * 256 + w * 32 + g * 4) = word;
        }
    }
}

// ---------------------------------------------------------------------------
// Exclusive scan of cnt_dst[256] -> dst_off[257], cursor copy. One block.
// ---------------------------------------------------------------------------
__global__ __launch_bounds__(256) void scan_k(
    const u32* __restrict__ cnt, u32* __restrict__ dst_off, u32* __restrict__ cursor)
{
    __shared__ u32 tmp[256];
    int t = threadIdx.x;
    u32 v = cnt[t];
    tmp[t] = v;
    __syncthreads();
    for (int off = 1; off < 256; off <<= 1) {
        u32 add = (t >= off) ? tmp[t - off] : 0u;
        __syncthreads();
        tmp[t] += add;
        __syncthreads();
    }
    u32 excl = tmp[t] - v;
    dst_off[t] = excl;
    cursor[t]  = excl;
    if (t == 255) dst_off[256] = tmp[255];
}

__global__ __launch_bounds__(256) void scatter_k(
    const int* __restrict__ dst, u32* __restrict__ cursor, u32* __restrict__ eidx)
{
    int e = blockIdx.x * 256 + threadIdx.x;
    if (e >= E_EDGES) return;
    u32 pos = atomicAdd(&cursor[dst[e]], 1u);
    eidx[pos] = (u32)e;
}

// ---------------------------------------------------------------------------
// Scores: one 64-lane wave per edge. lane l holds channels 4l..4l+3.
// 8-lane shuffle reduce -> per-head score; exp to ws; atomicAdd denom[d][h].
// ---------------------------------------------------------------------------
__global__ __launch_bounds__(256) void scores_k(
    const int* __restrict__ src, const int* __restrict__ dst,
    const u16* __restrict__ Qb, const u16* __restrict__ Kb,
    const unsigned char* __restrict__ T, const float* __restrict__ spd_w,
    float* __restrict__ ex, float* __restrict__ denom)
{
    int wid = blockIdx.x * 4 + (threadIdx.x >> 6);
    if (wid >= E_EDGES) return;
    int lane = threadIdx.x & 63;
    int s = src[wid], d = dst[wid];
    ushort4 q = *(const ushort4*)(Qb + (size_t)d * 256 + lane * 4);
    ushort4 k = *(const ushort4*)(Kb + (size_t)s * 256 + lane * 4);
    float p = bf2f(q.x) * bf2f(k.x) + bf2f(q.y) * bf2f(k.y)
            + bf2f(q.z) * bf2f(k.z) + bf2f(q.w) * bf2f(k.w);
    p += __shfl_xor(p, 1);
    p += __shfl_xor(p, 2);
    p += __shfl_xor(p, 4);
    if ((lane & 7) == 0) {
        int h = lane >> 3;
        int sp = (s < 256) ? (int)T[s * 256 + d] : 4;
        float sc = p * 0.17677669529663689f + spd_w[sp * 8 + h];
        float v = __expf(sc);   // no max-subtract: |sc| <~ 40, exact softmax identity
        ex[(size_t)wid * 8 + h] = v;
        atomicAdd(&denom[d * 8 + h], v);
    }
}

// ---------------------------------------------------------------------------
// Aggregate: blockIdx = d*8 + part; 32 waves per dst stride its CSR segment.
// lane l accumulates channels 4l..4l+3 (head = l>>3). LDS-reduce 4 waves,
// then one atomicAdd per channel per block into out_f32[d][ch].
// ---------------------------------------------------------------------------
__global__ __launch_bounds__(256) void aggregate_k(
    const int* __restrict__ src, const u32* __restrict__ eidx,
    const u32* __restrict__ dst_off, const float* __restrict__ ex,
    const float* __restrict__ denom, const u16* __restrict__ Vb,
    float* __restrict__ out)
{
    __shared__ float red[4 * 256];
    int d    = blockIdx.x >> 3;
    int part = blockIdx.x & 7;
    int t = threadIdx.x, lane = t & 63, wave = t >> 6;
    int h = lane >> 3;
    int gw = part * 4 + wave;              // 0..31
    u32 start = dst_off[d], end = dst_off[d + 1];
    float invden = 1.0f / denom[d * 8 + h];   // unused if segment empty
    float a0 = 0.f, a1 = 0.f, a2 = 0.f, a3 = 0.f;
    for (u32 i = start + gw; i < end; i += 32) {
        u32 e = eidx[i];
        float w = ex[(size_t)e * 8 + h] * invden;
        int s = src[e];
        ushort4 v = *(const ushort4*)(Vb + (size_t)s * 256 + lane * 4);
        a0 += w * bf2f(v.x); a1 += w * bf2f(v.y);
        a2 += w * bf2f(v.z); a3 += w * bf2f(v.w);
    }
    int ch = lane * 4;
    red[wave * 256 + ch + 0] = a0;
    red[wave * 256 + ch + 1] = a1;
    red[wave * 256 + ch + 2] = a2;
    red[wave * 256 + ch + 3] = a3;
    __syncthreads();
    float sAll = red[t] + red[256 + t] + red[512 + t] + red[768 + t];
    atomicAdd(&out[(size_t)d * 256 + t], sAll);
}

// ---------------------------------------------------------------------------
// LayerNorm: h = out(+only anchors) + x.  deg is constant per row -> cancels
// exactly under LN; skipped.  One wave per node, fp32 in/out.
// ---------------------------------------------------------------------------
__global__ __launch_bounds__(256) void ln_k(
    const float* __restrict__ x, const float* __restrict__ out,
    const float* __restrict__ gamma, const float* __restrict__ beta,
    float* __restrict__ y)
{
    int n = blockIdx.x * 4 + (threadIdx.x >> 6);
    if (n >= N_NODES) return;
    int lane = threadIdx.x & 63;
    int ch = lane * 4;
    float4 xv = *(const float4*)(x + (size_t)n * 256 + ch);
    float h0 = xv.x, h1 = xv.y, h2 = xv.z, h3 = xv.w;
    if (n < 256) {
        const float* op = out + (size_t)n * 256 + ch;
        h0 += op[0]; h1 += op[1]; h2 += op[2]; h3 += op[3];
    }
    float s = h0 + h1 + h2 + h3;
#pragma unroll
    for (int off = 1; off < 64; off <<= 1) s += __shfl_xor(s, off);
    float mu = s * (1.0f / 256.0f);
    float d0 = h0 - mu, d1 = h1 - mu, d2 = h2 - mu, d3 = h3 - mu;
    float q = d0 * d0 + d1 * d1 + d2 * d2 + d3 * d3;
#pragma unroll
    for (int off = 1; off < 64; off <<= 1) q += __shfl_xor(q, off);
    float rstd = rsqrtf(q * (1.0f / 256.0f) + 1e-5f);
    float4 gv = *(const float4*)(gamma + ch);
    float4 bv = *(const float4*)(beta + ch);
    float4 o;
    o.x = d0 * rstd * gv.x + bv.x;
    o.y = d1 * rstd * gv.y + bv.y;
    o.z = d2 * rstd * gv.z + bv.z;
    o.w = d3 * rstd * gv.w + bv.w;
    *(float4*)(y + (size_t)n * 256 + ch) = o;
}

// ---------------------------------------------------------------------------
extern "C" void kernel_launch(void* const* d_in, const int* in_sizes, int n_in,
                              void* d_out, int out_size, void* d_ws, size_t ws_size,
                              hipStream_t stream)
{
    const float* x     = (const float*)d_in[0];
    const int*   src   = (const int*)d_in[1];
    const int*   dst   = (const int*)d_in[2];
    const float* Wq    = (const float*)d_in[3];
    const float* bq    = (const float*)d_in[4];
    const float* Wk    = (const float*)d_in[5];
    const float* bk    = (const float*)d_in[6];
    const float* Wv    = (const float*)d_in[7];
    const float* bv    = (const float*)d_in[8];
    const float* spd_w = (const float*)d_in[9];
    const float* gamma = (const float*)d_in[10];
    const float* beta  = (const float*)d_in[11];
    float* y = (float*)d_out;

    char* ws = (char*)d_ws;
    // --- zeroed region [0, 279552) ---
    u32*   cnt_dst = (u32*)(ws + 0);          //   1024 B
    float* denom   = (float*)(ws + 1024);     //   8192 B
    float* outf    = (float*)(ws + 9216);     // 262144 B
    u32*   inmask  = (u32*)(ws + 271360);     //   8192 B  (ends 279552)
    // --- rest ---
    u32*   dst_off = (u32*)(ws + 279552);     //   1028 B
    u32*   cursor  = (u32*)(ws + 280832);     //   1024 B
    unsigned char* T = (unsigned char*)(ws + 281856); // 65536 B
    u32*   eidx    = (u32*)(ws + 347392);     // 1.2 MB
    float* ex      = (float*)(ws + 1547392);  // 9.6 MB
    u16*   Qb      = (u16*)(ws + 11147392);   // 128 KB
    u16*   Kb      = (u16*)(ws + 11278464);   // 25.6 MB
    u16*   Vb      = (u16*)(ws + 36878464);   // 25.6 MB
    u16*   xb      = (u16*)(ws + 62478464);   // 25.6 MB
    u16*   Wqb     = (u16*)(ws + 88078464);   // 128 KB
    u16*   Wkb     = (u16*)(ws + 88209536);   // 128 KB
    u16*   Wvb     = (u16*)(ws + 88340608);   // 128 KB (end ~88.5 MB)

    hipMemsetAsync(d_ws, 0, 279552, stream);

    dim3 blk(256);
    cvt_k<<<dim3(12500), blk, 0, stream>>>(x, xb, N_NODES * C_CH);
    cvt_k<<<dim3(64), blk, 0, stream>>>(Wq, Wqb, C_CH * C_CH);
    cvt_k<<<dim3(64), blk, 0, stream>>>(Wk, Wkb, C_CH * C_CH);
    cvt_k<<<dim3(64), blk, 0, stream>>>(Wv, Wvb, C_CH * C_CH);
    gemm_bt<<<dim3(4, 4),   blk, 0, stream>>>(xb, Wqb, bq, Qb, 256);
    gemm_bt<<<dim3(782, 4), blk, 0, stream>>>(xb, Wkb, bk, Kb, N_NODES);
    gemm_bt<<<dim3(782, 4), blk, 0, stream>>>(xb, Wvb, bv, Vb, N_NODES);
    edge_prep<<<dim3((E_EDGES + 255) / 256), blk, 0, stream>>>(src, dst, cnt_dst, inmask);
    spd_levels<<<dim3(1), blk, 0, stream>>>(inmask, T);
    scan_k<<<dim3(1), blk, 0, stream>>>(cnt_dst, dst_off, cursor);
    scatter_k<<<dim3((E_EDGES + 255) / 256), blk, 0, stream>>>(dst, cursor, eidx);
    scores_k<<<dim3((E_EDGES + 3) / 4), blk, 0, stream>>>(src, dst, Qb, Kb, T, spd_w, ex, denom);
    aggregate_k<<<dim3(256 * 8), blk, 0, stream>>>(src, eidx, dst_off, ex, denom, Vb, outf);
    ln_k<<<dim3((N_NODES + 3) / 4), blk, 0, stream>>>(x, outf, gamma, beta, y);
}

// Round 3
// 342.246 us; speedup vs baseline: 1.7868x; 1.7868x over previous
//
#include <hip/hip_runtime.h>
#include <stdint.h>

#define N_NODES 50000
#define E_EDGES 300000
#define C_CH    256
#define H_HEADS 8
#define NB_SORT 256      // blocks in counting sort
#define CHUNK   1172     // edges per sort block (256*1172 >= 300000)

typedef unsigned short u16;
typedef unsigned int   u32;

typedef __attribute__((ext_vector_type(8))) short  v8s;   // 8 bf16 (MFMA A/B frag)
typedef __attribute__((ext_vector_type(4))) float  v4f;   // MFMA C/D frag

__device__ __forceinline__ float bf2f(u16 v) {
    union { u32 u; float f; } x; x.u = ((u32)v) << 16; return x.f;
}
__device__ __forceinline__ u16 f2bf(float f) {
    union { float f; u32 u; } x; x.f = f;
    u32 r = (x.u + 0x7FFFu + ((x.u >> 16) & 1u)) >> 16;
    return (u16)r;
}

// ---------------------------------------------------------------------------
// fp32 -> bf16 convert (n multiple of 4)
// ---------------------------------------------------------------------------
__global__ __launch_bounds__(256) void cvt_k(
    const float* __restrict__ in, u16* __restrict__ out, int n)
{
    int i = (blockIdx.x * 256 + threadIdx.x) * 4;
    if (i >= n) return;
    float4 v = *(const float4*)(in + i);
    ushort4 o;
    o.x = f2bf(v.x); o.y = f2bf(v.y); o.z = f2bf(v.z); o.w = f2bf(v.w);
    *(ushort4*)(out + i) = o;
}

// ---------------------------------------------------------------------------
// GEMM: OUT[M,256] = X[M,256] @ W[256,256]^T + bias   (bf16 in, fp32 acc,
// bf16 out). 64x64 tile per block (4 waves), BK=32, mfma_f32_16x16x32_bf16.
// ---------------------------------------------------------------------------
#define LDT 40   // LDS row stride in bf16 elems (80 B: 16B-aligned, 2-way max)

__global__ __launch_bounds__(256) void gemm_bt(
    const u16* __restrict__ X, const u16* __restrict__ W,
    const float* __restrict__ bias, u16* __restrict__ OUT, int M)
{
    __shared__ u16 As[64 * LDT];
    __shared__ u16 Bs[64 * LDT];
    const int t    = threadIdx.x;
    const int m0   = blockIdx.x * 64;
    const int n0   = blockIdx.y * 64;
    const int lane = t & 63, wave = t >> 6;
    const int quad = lane >> 4, l15 = lane & 15;

    v4f acc[4];
#pragma unroll
    for (int i = 0; i < 4; i++) acc[i] = (v4f)(0.0f);

    const int lrow = t >> 2;         // 0..63
    const int lseg = (t & 3) * 8;    // 0,8,16,24

    for (int k0 = 0; k0 < 256; k0 += 32) {
        int gr = m0 + lrow;
        uint4 av = make_uint4(0u, 0u, 0u, 0u);
        if (gr < M) av = *(const uint4*)(X + (size_t)gr * 256 + k0 + lseg);
        *(uint4*)(As + lrow * LDT + lseg) = av;
        uint4 bv = *(const uint4*)(W + (size_t)(n0 + lrow) * 256 + k0 + lseg);
        *(uint4*)(Bs + lrow * LDT + lseg) = bv;
        __syncthreads();

        v8s a = *(const v8s*)(As + (wave * 16 + l15) * LDT + quad * 8);
#pragma unroll
        for (int nt = 0; nt < 4; nt++) {
            v8s b = *(const v8s*)(Bs + (nt * 16 + l15) * LDT + quad * 8);
            acc[nt] = __builtin_amdgcn_mfma_f32_16x16x32_bf16(a, b, acc[nt], 0, 0, 0);
        }
        __syncthreads();
    }

#pragma unroll
    for (int nt = 0; nt < 4; nt++) {
        int n = n0 + nt * 16 + l15;
        float bi = bias[n];
#pragma unroll
        for (int r = 0; r < 4; r++) {
            int m = m0 + wave * 16 + quad * 4 + r;   // C/D: row=quad*4+reg, col=lane&15
            if (m < M) OUT[(size_t)m * 256 + n] = f2bf(acc[nt][r] + bi);
        }
    }
}

// ---------------------------------------------------------------------------
// Counting sort pass 1: per-block LDS histogram of dst -> blockhist[b][256].
// Also builds the anchor adjacency bitmask (rare atomicOr, ~1.5k edges).
// ---------------------------------------------------------------------------
__global__ __launch_bounds__(256) void hist_k(
    const int* __restrict__ src, const int* __restrict__ dst,
    u32* __restrict__ blockhist, u32* __restrict__ inmask)
{
    __shared__ u32 hist[256];
    int t = threadIdx.x, b = blockIdx.x;
    hist[t] = 0;
    __syncthreads();
    int start = b * CHUNK;
    int end = start + CHUNK; if (end > E_EDGES) end = E_EDGES;
    for (int e = start + t; e < end; e += 256) {
        int d = dst[e];
        atomicAdd(&hist[d], 1u);            // LDS atomic: cheap
        int s = src[e];
        if (s < 256) atomicOr(&inmask[d * 8 + (s >> 5)], 1u << (s & 31));
    }
    __syncthreads();
    blockhist[b * 256 + t] = hist[t];
}

// ---------------------------------------------------------------------------
// Counting sort pass 2 (1 block): dst totals, exclusive scan -> dst_off[257],
// per-(block,dst) base offsets -> blockbase[b][d]. Deterministic, no atomics.
// ---------------------------------------------------------------------------
__global__ __launch_bounds__(256) void off_k(
    const u32* __restrict__ blockhist, u32* __restrict__ dst_off,
    u32* __restrict__ blockbase)
{
    __shared__ u32 tmp[256];
    int d = threadIdx.x;
    u32 tot = 0;
    for (int b = 0; b < NB_SORT; b++) tot += blockhist[b * 256 + d];
    tmp[d] = tot;
    __syncthreads();
    for (int off = 1; off < 256; off <<= 1) {
        u32 add = (d >= off) ? tmp[d - off] : 0u;
        __syncthreads();
        tmp[d] += add;
        __syncthreads();
    }
    u32 excl = tmp[d] - tot;
    dst_off[d] = excl;
    if (d == 255) dst_off[256] = tmp[255];
    u32 base = excl;
    for (int b = 0; b < NB_SORT; b++) {
        blockbase[b * 256 + d] = base;
        base += blockhist[b * 256 + d];
    }
}

// ---------------------------------------------------------------------------
// Counting sort pass 3: scatter edge ids using LDS cursors (no global atomics).
// ---------------------------------------------------------------------------
__global__ __launch_bounds__(256) void scatter2_k(
    const int* __restrict__ dst, const u32* __restrict__ blockbase,
    u32* __restrict__ eidx)
{
    __shared__ u32 cur[256];
    int t = threadIdx.x, b = blockIdx.x;
    cur[t] = blockbase[b * 256 + t];
    __syncthreads();
    int start = b * CHUNK;
    int end = start + CHUNK; if (end > E_EDGES) end = E_EDGES;
    for (int e = start + t; e < end; e += 256) {
        u32 pos = atomicAdd(&cur[dst[e]], 1u);   // LDS atomic
        eidx[pos] = (u32)e;
    }
}

// ---------------------------------------------------------------------------
// SPD: 3-level exact-length reachability on the 256-anchor subgraph.
// T[i*256+m] = first k in {1,2,3} with walk of length k from m to i, else 4.
// spd[e] = T[src][dst] for src<256, else 4.  One block.
// ---------------------------------------------------------------------------
__global__ __launch_bounds__(256) void spd_levels(
    const u32* __restrict__ inmask, unsigned char* __restrict__ T)
{
    __shared__ u32 F1[256][8], F2[256][8], F3[256][8];
    int i = threadIdx.x;
#pragma unroll
    for (int w = 0; w < 8; w++) { F1[i][w] = inmask[i * 8 + w]; F2[i][w] = 0; F3[i][w] = 0; }
    __syncthreads();
    for (int w = 0; w < 8; w++) {
        u32 m = F1[i][w];
        while (m) {
            int b = __ffs(m) - 1; m &= m - 1;
            int s = w * 32 + b;
#pragma unroll
            for (int j = 0; j < 8; j++) F2[i][j] |= F1[s][j];
        }
    }
    __syncthreads();
    for (int w = 0; w < 8; w++) {
        u32 m = F1[i][w];
        while (m) {
            int b = __ffs(m) - 1; m &= m - 1;
            int s = w * 32 + b;
#pragma unroll
            for (int j = 0; j < 8; j++) F3[i][j] |= F2[s][j];
        }
    }
    __syncthreads();
    for (int w = 0; w < 8; w++) {
        u32 f1 = F1[i][w], f2 = F2[i][w], f3 = F3[i][w];
#pragma unroll
        for (int g = 0; g < 8; g++) {
            u32 word = 0;
#pragma unroll
            for (int b = 0; b < 4; b++) {
                int bit = g * 4 + b;
                u32 k = ((f1 >> bit) & 1u) ? 1u : ((f2 >> bit) & 1u) ? 2u
                       : ((f3 >> bit) & 1u) ? 3u : 4u;
                word |= k << (8 * b);
            }
            *(u32*)(T + i * 256 + w * 32 + g * 4) = word;
        }
    }
}

// ---------------------------------------------------------------------------
// Scores: one 64-lane wave per edge; lane l holds channels 4l..4l+3.
// 8-lane shuffle reduce -> per-head score; exp written to ex. NO atomics.
// ---------------------------------------------------------------------------
__global__ __launch_bounds__(256) void scores_k(
    const int* __restrict__ src, const int* __restrict__ dst,
    const u16* __restrict__ Qb, const u16* __restrict__ Kb,
    const unsigned char* __restrict__ T, const float* __restrict__ spd_w,
    float* __restrict__ ex)
{
    int wid = blockIdx.x * 4 + (threadIdx.x >> 6);
    if (wid >= E_EDGES) return;
    int lane = threadIdx.x & 63;
    int s = src[wid], d = dst[wid];
    ushort4 q = *(const ushort4*)(Qb + (size_t)d * 256 + lane * 4);
    ushort4 k = *(const ushort4*)(Kb + (size_t)s * 256 + lane * 4);
    float p = bf2f(q.x) * bf2f(k.x) + bf2f(q.y) * bf2f(k.y)
            + bf2f(q.z) * bf2f(k.z) + bf2f(q.w) * bf2f(k.w);
    p += __shfl_xor(p, 1);
    p += __shfl_xor(p, 2);
    p += __shfl_xor(p, 4);
    if ((lane & 7) == 0) {
        int h = lane >> 3;
        int sp = (s < 256) ? (int)T[s * 256 + d] : 4;
        float sc = p * 0.17677669529663689f + spd_w[sp * 8 + h];
        ex[(size_t)wid * 8 + h] = __expf(sc);  // |sc| small: exact softmax identity
    }
}

// ---------------------------------------------------------------------------
// Aggregate: blockIdx = d*8 + part; 32 waves per dst stride its CSR segment.
// Accumulates UNNORMALIZED sums + partial denominators (normalization in ln_k).
// Per block: 256 atomics to out (8-deep chains) + 8 to denom — no contention.
// ---------------------------------------------------------------------------
__global__ __launch_bounds__(256) void aggregate_k(
    const int* __restrict__ src, const u32* __restrict__ eidx,
    const u32* __restrict__ dst_off, const float* __restrict__ ex,
    const u16* __restrict__ Vb, float* __restrict__ out,
    float* __restrict__ denom)
{
    __shared__ float red[4 * 256];
    __shared__ float dred[4 * 8];
    int d    = blockIdx.x >> 3;
    int part = blockIdx.x & 7;
    int t = threadIdx.x, lane = t & 63, wave = t >> 6;
    int h = lane >> 3;
    int gw = part * 4 + wave;              // 0..31
    u32 start = dst_off[d], end = dst_off[d + 1];
    float a0 = 0.f, a1 = 0.f, a2 = 0.f, a3 = 0.f, dsum = 0.f;
    for (u32 i = start + gw; i < end; i += 32) {
        u32 e = eidx[i];
        float w = ex[(size_t)e * 8 + h];
        int s = src[e];
        ushort4 v = *(const ushort4*)(Vb + (size_t)s * 256 + lane * 4);
        a0 += w * bf2f(v.x); a1 += w * bf2f(v.y);
        a2 += w * bf2f(v.z); a3 += w * bf2f(v.w);
        dsum += w;
    }
    int ch = lane * 4;
    red[wave * 256 + ch + 0] = a0;
    red[wave * 256 + ch + 1] = a1;
    red[wave * 256 + ch + 2] = a2;
    red[wave * 256 + ch + 3] = a3;
    if ((lane & 7) == 0) dred[wave * 8 + h] = dsum;
    __syncthreads();
    float sAll = red[t] + red[256 + t] + red[512 + t] + red[768 + t];
    atomicAdd(&out[(size_t)d * 256 + t], sAll);
    if (t < 8) {
        float ds = dred[t] + dred[8 + t] + dred[16 + t] + dred[24 + t];
        atomicAdd(&denom[d * 8 + t], ds);
    }
}

// ---------------------------------------------------------------------------
// LayerNorm: h = out/denom (anchors only) + x.  deg is constant per row ->
// cancels exactly under LN; skipped.  One wave per node, fp32 in/out.
// ---------------------------------------------------------------------------
__global__ __launch_bounds__(256) void ln_k(
    const float* __restrict__ x, const float* __restrict__ out,
    const float* __restrict__ denom, const float* __restrict__ gamma,
    const float* __restrict__ beta, float* __restrict__ y)
{
    int n = blockIdx.x * 4 + (threadIdx.x >> 6);
    if (n >= N_NODES) return;
    int lane = threadIdx.x & 63;
    int ch = lane * 4;
    float4 xv = *(const float4*)(x + (size_t)n * 256 + ch);
    float h0 = xv.x, h1 = xv.y, h2 = xv.z, h3 = xv.w;
    if (n < 256) {
        float den = denom[n * 8 + (lane >> 3)];
        float inv = (den > 0.f) ? 1.0f / den : 0.0f;
        const float* op = out + (size_t)n * 256 + ch;
        h0 += op[0] * inv; h1 += op[1] * inv;
        h2 += op[2] * inv; h3 += op[3] * inv;
    }
    float s = h0 + h1 + h2 + h3;
#pragma unroll
    for (int off = 1; off < 64; off <<= 1) s += __shfl_xor(s, off);
    float mu = s * (1.0f / 256.0f);
    float d0 = h0 - mu, d1 = h1 - mu, d2 = h2 - mu, d3 = h3 - mu;
    float q = d0 * d0 + d1 * d1 + d2 * d2 + d3 * d3;
#pragma unroll
    for (int off = 1; off < 64; off <<= 1) q += __shfl_xor(q, off);
    float rstd = rsqrtf(q * (1.0f / 256.0f) + 1e-5f);
    float4 gv = *(const float4*)(gamma + ch);
    float4 bv = *(const float4*)(beta + ch);
    float4 o;
    o.x = d0 * rstd * gv.x + bv.x;
    o.y = d1 * rstd * gv.y + bv.y;
    o.z = d2 * rstd * gv.z + bv.z;
    o.w = d3 * rstd * gv.w + bv.w;
    *(float4*)(y + (size_t)n * 256 + ch) = o;
}

// ---------------------------------------------------------------------------
extern "C" void kernel_launch(void* const* d_in, const int* in_sizes, int n_in,
                              void* d_out, int out_size, void* d_ws, size_t ws_size,
                              hipStream_t stream)
{
    const float* x     = (const float*)d_in[0];
    const int*   src   = (const int*)d_in[1];
    const int*   dst   = (const int*)d_in[2];
    const float* Wq    = (const float*)d_in[3];
    const float* bq    = (const float*)d_in[4];
    const float* Wk    = (const float*)d_in[5];
    const float* bk    = (const float*)d_in[6];
    const float* Wv    = (const float*)d_in[7];
    const float* bv    = (const float*)d_in[8];
    const float* spd_w = (const float*)d_in[9];
    const float* gamma = (const float*)d_in[10];
    const float* beta  = (const float*)d_in[11];
    float* y = (float*)d_out;

    char* ws = (char*)d_ws;
    // --- zeroed region [0, 278528) ---
    float* denom     = (float*)(ws + 0);          //   8192 B
    float* outf      = (float*)(ws + 8192);       // 262144 B
    u32*   inmask    = (u32*)(ws + 270336);       //   8192 B (zero region ends 278528)
    // --- rest (all written before read) ---
    u32*   dst_off   = (u32*)(ws + 278528);       //   1028 B (pad to 2048)
    unsigned char* T = (unsigned char*)(ws + 280576); // 65536 B
    u32*   blockhist = (u32*)(ws + 346112);       // 262144 B
    u32*   blockbase = (u32*)(ws + 608256);       // 262144 B
    u32*   eidx      = (u32*)(ws + 870400);       // 1.2 MB
    float* ex        = (float*)(ws + 2070400);    // 9.6 MB
    u16*   Qb        = (u16*)(ws + 11670400);     // 128 KB
    u16*   Kb        = (u16*)(ws + 11801472);     // 25.6 MB
    u16*   Vb        = (u16*)(ws + 37401472);     // 25.6 MB
    u16*   xb        = (u16*)(ws + 63001472);     // 25.6 MB
    u16*   Wqb       = (u16*)(ws + 88601472);     // 128 KB
    u16*   Wkb       = (u16*)(ws + 88732544);     // 128 KB
    u16*   Wvb       = (u16*)(ws + 88863616);     // 128 KB (end ~88.99 MB)

    hipMemsetAsync(d_ws, 0, 278528, stream);

    dim3 blk(256);
    cvt_k<<<dim3(12500), blk, 0, stream>>>(x, xb, N_NODES * C_CH);
    cvt_k<<<dim3(64), blk, 0, stream>>>(Wq, Wqb, C_CH * C_CH);
    cvt_k<<<dim3(64), blk, 0, stream>>>(Wk, Wkb, C_CH * C_CH);
    cvt_k<<<dim3(64), blk, 0, stream>>>(Wv, Wvb, C_CH * C_CH);
    gemm_bt<<<dim3(4, 4),   blk, 0, stream>>>(xb, Wqb, bq, Qb, 256);
    gemm_bt<<<dim3(782, 4), blk, 0, stream>>>(xb, Wkb, bk, Kb, N_NODES);
    gemm_bt<<<dim3(782, 4), blk, 0, stream>>>(xb, Wvb, bv, Vb, N_NODES);
    hist_k<<<dim3(NB_SORT), blk, 0, stream>>>(src, dst, blockhist, inmask);
    off_k<<<dim3(1), blk, 0, stream>>>(blockhist, dst_off, blockbase);
    spd_levels<<<dim3(1), blk, 0, stream>>>(inmask, T);
    scatter2_k<<<dim3(NB_SORT), blk, 0, stream>>>(dst, blockbase, eidx);
    scores_k<<<dim3((E_EDGES + 3) / 4), blk, 0, stream>>>(src, dst, Qb, Kb, T, spd_w, ex);
    aggregate_k<<<dim3(256 * 8), blk, 0, stream>>>(src, eidx, dst_off, ex, Vb, outf, denom);
    ln_k<<<dim3((N_NODES + 3) / 4), blk, 0, stream>>>(x, outf, denom, gamma, beta, y);
}

// Round 4
// 276.612 us; speedup vs baseline: 2.2108x; 1.2373x over previous
//
#include <hip/hip_runtime.h>
#include <stdint.h>

#define N_NODES 50000
#define E_EDGES 300000
#define C_CH    256
#define H_HEADS 8
#define NB_SORT 256      // blocks in counting sort
#define CHUNK   1172     // edges per sort block (256*1172 >= 300000)

typedef unsigned short u16;
typedef unsigned int   u32;

typedef __attribute__((ext_vector_type(8))) short  v8s;   // 8 bf16 (MFMA A/B frag)
typedef __attribute__((ext_vector_type(4))) float  v4f;   // MFMA C/D frag

__device__ __forceinline__ float bf2f(u16 v) {
    union { u32 u; float f; } x; x.u = ((u32)v) << 16; return x.f;
}
__device__ __forceinline__ u16 f2bf(float f) {
    union { float f; u32 u; } x; x.f = f;
    u32 r = (x.u + 0x7FFFu + ((x.u >> 16) & 1u)) >> 16;
    return (u16)r;
}
__device__ __forceinline__ u32 pack2(float a, float b) {
    return (u32)f2bf(a) | ((u32)f2bf(b) << 16);
}

// ---------------------------------------------------------------------------
// Weight convert: 3 × [256,256] fp32 -> bf16 in one launch (192 blocks).
// ---------------------------------------------------------------------------
__global__ __launch_bounds__(256) void cvt_w(
    const float* __restrict__ Wq, const float* __restrict__ Wk,
    const float* __restrict__ Wv, u16* __restrict__ Wqb,
    u16* __restrict__ Wkb, u16* __restrict__ Wvb)
{
    int b = blockIdx.x;
    const float* in = (b < 64) ? Wq : (b < 128) ? Wk : Wv;
    u16* out = (b < 64) ? Wqb : (b < 128) ? Wkb : Wvb;
    int i = (b & 63) * 1024 + threadIdx.x * 4;
    float4 v = *(const float4*)(in + i);
    ushort4 o;
    o.x = f2bf(v.x); o.y = f2bf(v.y); o.z = f2bf(v.z); o.w = f2bf(v.w);
    *(ushort4*)(out + i) = o;
}

// ---------------------------------------------------------------------------
// GEMM Q: OUT[M,256] = X_f32[M,256] @ W_bf16[256,256]^T + bias (fp32 A
// converted inline during staging). 64x64 tile, mfma_f32_16x16x32_bf16.
// ---------------------------------------------------------------------------
#define LDT 40   // LDS row stride in bf16 elems (80 B: 16B-aligned, 2-way max)

__global__ __launch_bounds__(256) void gemm_q(
    const float* __restrict__ X, const u16* __restrict__ W,
    const float* __restrict__ bias, u16* __restrict__ OUT, int M)
{
    __shared__ u16 As[64 * LDT];
    __shared__ u16 Bs[64 * LDT];
    const int t    = threadIdx.x;
    const int m0   = blockIdx.x * 64;
    const int n0   = blockIdx.y * 64;
    const int lane = t & 63, wave = t >> 6;
    const int quad = lane >> 4, l15 = lane & 15;

    v4f acc[4];
#pragma unroll
    for (int i = 0; i < 4; i++) acc[i] = (v4f)(0.0f);

    const int lrow = t >> 2;         // 0..63
    const int lseg = (t & 3) * 8;    // 0,8,16,24

    for (int k0 = 0; k0 < 256; k0 += 32) {
        int gr = m0 + lrow;
        float4 f0 = make_float4(0.f,0.f,0.f,0.f), f1 = f0;
        if (gr < M) {
            const float* xp = X + (size_t)gr * 256 + k0 + lseg;
            f0 = *(const float4*)(xp);
            f1 = *(const float4*)(xp + 4);
        }
        uint4 ap;
        ap.x = pack2(f0.x, f0.y); ap.y = pack2(f0.z, f0.w);
        ap.z = pack2(f1.x, f1.y); ap.w = pack2(f1.z, f1.w);
        *(uint4*)(As + lrow * LDT + lseg) = ap;
        *(uint4*)(Bs + lrow * LDT + lseg) =
            *(const uint4*)(W + (size_t)(n0 + lrow) * 256 + k0 + lseg);
        __syncthreads();

        v8s a = *(const v8s*)(As + (wave * 16 + l15) * LDT + quad * 8);
#pragma unroll
        for (int nt = 0; nt < 4; nt++) {
            v8s b = *(const v8s*)(Bs + (nt * 16 + l15) * LDT + quad * 8);
            acc[nt] = __builtin_amdgcn_mfma_f32_16x16x32_bf16(a, b, acc[nt], 0, 0, 0);
        }
        __syncthreads();
    }

#pragma unroll
    for (int nt = 0; nt < 4; nt++) {
        int n = n0 + nt * 16 + l15;
        float bi = bias[n];
#pragma unroll
        for (int r = 0; r < 4; r++) {
            int m = m0 + wave * 16 + quad * 4 + r;   // C/D: row=quad*4+reg, col=lane&15
            if (m < M) OUT[(size_t)m * 256 + n] = f2bf(acc[nt][r] + bi);
        }
    }
}

// ---------------------------------------------------------------------------
// GEMM KV: stage A (fp32->bf16) ONCE, two B tiles, two accumulator sets.
// Produces K and V in one pass over X.
// ---------------------------------------------------------------------------
__global__ __launch_bounds__(256) void gemm_kv(
    const float* __restrict__ X, const u16* __restrict__ Wk,
    const u16* __restrict__ Wv, const float* __restrict__ bk,
    const float* __restrict__ bv, u16* __restrict__ K, u16* __restrict__ V,
    int M)
{
    __shared__ u16 As[64 * LDT];
    __shared__ u16 Bk[64 * LDT];
    __shared__ u16 Bv[64 * LDT];
    const int t    = threadIdx.x;
    const int m0   = blockIdx.x * 64;
    const int n0   = blockIdx.y * 64;
    const int lane = t & 63, wave = t >> 6;
    const int quad = lane >> 4, l15 = lane & 15;

    v4f aK[4], aV[4];
#pragma unroll
    for (int i = 0; i < 4; i++) { aK[i] = (v4f)(0.0f); aV[i] = (v4f)(0.0f); }

    const int lrow = t >> 2;
    const int lseg = (t & 3) * 8;

    for (int k0 = 0; k0 < 256; k0 += 32) {
        int gr = m0 + lrow;
        float4 f0 = make_float4(0.f,0.f,0.f,0.f), f1 = f0;
        if (gr < M) {
            const float* xp = X + (size_t)gr * 256 + k0 + lseg;
            f0 = *(const float4*)(xp);
            f1 = *(const float4*)(xp + 4);
        }
        uint4 ap;
        ap.x = pack2(f0.x, f0.y); ap.y = pack2(f0.z, f0.w);
        ap.z = pack2(f1.x, f1.y); ap.w = pack2(f1.z, f1.w);
        *(uint4*)(As + lrow * LDT + lseg) = ap;
        *(uint4*)(Bk + lrow * LDT + lseg) =
            *(const uint4*)(Wk + (size_t)(n0 + lrow) * 256 + k0 + lseg);
        *(uint4*)(Bv + lrow * LDT + lseg) =
            *(const uint4*)(Wv + (size_t)(n0 + lrow) * 256 + k0 + lseg);
        __syncthreads();

        v8s a = *(const v8s*)(As + (wave * 16 + l15) * LDT + quad * 8);
#pragma unroll
        for (int nt = 0; nt < 4; nt++) {
            v8s b0 = *(const v8s*)(Bk + (nt * 16 + l15) * LDT + quad * 8);
            aK[nt] = __builtin_amdgcn_mfma_f32_16x16x32_bf16(a, b0, aK[nt], 0, 0, 0);
            v8s b1 = *(const v8s*)(Bv + (nt * 16 + l15) * LDT + quad * 8);
            aV[nt] = __builtin_amdgcn_mfma_f32_16x16x32_bf16(a, b1, aV[nt], 0, 0, 0);
        }
        __syncthreads();
    }

#pragma unroll
    for (int nt = 0; nt < 4; nt++) {
        int n = n0 + nt * 16 + l15;
        float bik = bk[n], biv = bv[n];
#pragma unroll
        for (int r = 0; r < 4; r++) {
            int m = m0 + wave * 16 + quad * 4 + r;
            if (m < M) {
                K[(size_t)m * 256 + n] = f2bf(aK[nt][r] + bik);
                V[(size_t)m * 256 + n] = f2bf(aV[nt][r] + biv);
            }
        }
    }
}

// ---------------------------------------------------------------------------
// Counting sort pass 1: per-block LDS histogram of dst -> blockhist[b][256].
// Also builds the anchor adjacency bitmask (rare atomicOr, ~1.5k edges).
// ---------------------------------------------------------------------------
__global__ __launch_bounds__(256) void hist_k(
    const int* __restrict__ src, const int* __restrict__ dst,
    u32* __restrict__ blockhist, u32* __restrict__ inmask)
{
    __shared__ u32 hist[256];
    int t = threadIdx.x, b = blockIdx.x;
    hist[t] = 0;
    __syncthreads();
    int start = b * CHUNK;
    int end = start + CHUNK; if (end > E_EDGES) end = E_EDGES;
    for (int e = start + t; e < end; e += 256) {
        int d = dst[e];
        atomicAdd(&hist[d], 1u);            // LDS atomic: cheap
        int s = src[e];
        if (s < 256) atomicOr(&inmask[d * 8 + (s >> 5)], 1u << (s & 31));
    }
    __syncthreads();
    blockhist[b * 256 + t] = hist[t];
}

// ---------------------------------------------------------------------------
// Counting sort pass 2 (1 block): dst totals, exclusive scan -> dst_off[257],
// per-(block,dst) base offsets -> blockbase[b][d]. Deterministic, no atomics.
// ---------------------------------------------------------------------------
__global__ __launch_bounds__(256) void off_k(
    const u32* __restrict__ blockhist, u32* __restrict__ dst_off,
    u32* __restrict__ blockbase)
{
    __shared__ u32 tmp[256];
    int d = threadIdx.x;
    u32 tot = 0;
    for (int b = 0; b < NB_SORT; b++) tot += blockhist[b * 256 + d];
    tmp[d] = tot;
    __syncthreads();
    for (int off = 1; off < 256; off <<= 1) {
        u32 add = (d >= off) ? tmp[d - off] : 0u;
        __syncthreads();
        tmp[d] += add;
        __syncthreads();
    }
    u32 excl = tmp[d] - tot;
    dst_off[d] = excl;
    if (d == 255) dst_off[256] = tmp[255];
    u32 base = excl;
    for (int b = 0; b < NB_SORT; b++) {
        blockbase[b * 256 + d] = base;
        base += blockhist[b * 256 + d];
    }
}

// ---------------------------------------------------------------------------
// Counting sort pass 3: scatter edge ids using LDS cursors (no global atomics).
// ---------------------------------------------------------------------------
__global__ __launch_bounds__(256) void scatter2_k(
    const int* __restrict__ dst, const u32* __restrict__ blockbase,
    u32* __restrict__ eidx)
{
    __shared__ u32 cur[256];
    int t = threadIdx.x, b = blockIdx.x;
    cur[t] = blockbase[b * 256 + t];
    __syncthreads();
    int start = b * CHUNK;
    int end = start + CHUNK; if (end > E_EDGES) end = E_EDGES;
    for (int e = start + t; e < end; e += 256) {
        u32 pos = atomicAdd(&cur[dst[e]], 1u);   // LDS atomic
        eidx[pos] = (u32)e;
    }
}

// ---------------------------------------------------------------------------
// SPD: 3-level exact-length reachability on the 256-anchor subgraph.
// T[i*256+m] = first k in {1,2,3} with walk of length k from m to i, else 4.
// spd[e] = T[src][dst] for src<256, else 4.  One block.
// ---------------------------------------------------------------------------
__global__ __launch_bounds__(256) void spd_levels(
    const u32* __restrict__ inmask, unsigned char* __restrict__ T)
{
    __shared__ u32 F1[256][8], F2[256][8], F3[256][8];
    int i = threadIdx.x;
#pragma unroll
    for (int w = 0; w < 8; w++) { F1[i][w] = inmask[i * 8 + w]; F2[i][w] = 0; F3[i][w] = 0; }
    __syncthreads();
    for (int w = 0; w < 8; w++) {
        u32 m = F1[i][w];
        while (m) {
            int b = __ffs(m) - 1; m &= m - 1;
            int s = w * 32 + b;
#pragma unroll
            for (int j = 0; j < 8; j++) F2[i][j] |= F1[s][j];
        }
    }
    __syncthreads();
    for (int w = 0; w < 8; w++) {
        u32 m = F1[i][w];
        while (m) {
            int b = __ffs(m) - 1; m &= m - 1;
            int s = w * 32 + b;
#pragma unroll
            for (int j = 0; j < 8; j++) F3[i][j] |= F2[s][j];
        }
    }
    __syncthreads();
    for (int w = 0; w < 8; w++) {
        u32 f1 = F1[i][w], f2 = F2[i][w], f3 = F3[i][w];
#pragma unroll
        for (int g = 0; g < 8; g++) {
            u32 word = 0;
#pragma unroll
            for (int b = 0; b < 4; b++) {
                int bit = g * 4 + b;
                u32 k = ((f1 >> bit) & 1u) ? 1u : ((f2 >> bit) & 1u) ? 2u
                       : ((f3 >> bit) & 1u) ? 3u : 4u;
                word |= k << (8 * b);
            }
            *(u32*)(T + i * 256 + w * 32 + g * 4) = word;
        }
    }
}

// ---------------------------------------------------------------------------
// Fused scores+aggregate: blockIdx = d*8 + part; 32 waves per dst stride its
// CSR segment. Q[d] is loaded ONCE per thread (block-invariant). Per edge:
// gather K[s] -> dot per head (shuffle) -> +spd bias -> exp -> gather V[s],
// accumulate unnormalized sums + partial denominators. No ex round-trip.
// ---------------------------------------------------------------------------
__global__ __launch_bounds__(256) void agg_k(
    const int* __restrict__ src, const u32* __restrict__ eidx,
    const u32* __restrict__ dst_off, const u16* __restrict__ Qb,
    const u16* __restrict__ Kb, const u16* __restrict__ Vb,
    const unsigned char* __restrict__ T, const float* __restrict__ spd_w,
    float* __restrict__ out, float* __restrict__ denom)
{
    __shared__ float red[4 * 256];
    __shared__ float dred[4 * 8];
    int d    = blockIdx.x >> 3;
    int part = blockIdx.x & 7;
    int t = threadIdx.x, lane = t & 63, wave = t >> 6;
    int h = lane >> 3;
    int gw = part * 4 + wave;              // 0..31
    u32 start = dst_off[d], end = dst_off[d + 1];

    ushort4 q = *(const ushort4*)(Qb + (size_t)d * 256 + lane * 4);
    float q0 = bf2f(q.x), q1 = bf2f(q.y), q2 = bf2f(q.z), q3 = bf2f(q.w);
    float sw = spd_w[4 * 8 + h];           // spd=4 bias (src>=256, ~98.5% of edges)

    float a0 = 0.f, a1 = 0.f, a2 = 0.f, a3 = 0.f, dsum = 0.f;
    for (u32 i = start + gw; i < end; i += 32) {
        u32 e = eidx[i];                   // wave-uniform (scalar load)
        int s = src[e];                    // wave-uniform
        ushort4 kv = *(const ushort4*)(Kb + (size_t)s * 256 + lane * 4);
        ushort4 vv = *(const ushort4*)(Vb + (size_t)s * 256 + lane * 4);
        float p = q0 * bf2f(kv.x) + q1 * bf2f(kv.y)
                + q2 * bf2f(kv.z) + q3 * bf2f(kv.w);
        p += __shfl_xor(p, 1);
        p += __shfl_xor(p, 2);
        p += __shfl_xor(p, 4);
        float bias = (s < 256) ? spd_w[(int)T[s * 256 + d] * 8 + h] : sw;
        float w = __expf(p * 0.17677669529663689f + bias);
        a0 += w * bf2f(vv.x); a1 += w * bf2f(vv.y);
        a2 += w * bf2f(vv.z); a3 += w * bf2f(vv.w);
        dsum += w;
    }
    int ch = lane * 4;
    red[wave * 256 + ch + 0] = a0;
    red[wave * 256 + ch + 1] = a1;
    red[wave * 256 + ch + 2] = a2;
    red[wave * 256 + ch + 3] = a3;
    if ((lane & 7) == 0) dred[wave * 8 + h] = dsum;
    __syncthreads();
    float sAll = red[t] + red[256 + t] + red[512 + t] + red[768 + t];
    atomicAdd(&out[(size_t)d * 256 + t], sAll);
    if (t < 8) {
        float ds = dred[t] + dred[8 + t] + dred[16 + t] + dred[24 + t];
        atomicAdd(&denom[d * 8 + t], ds);
    }
}

// ---------------------------------------------------------------------------
// LayerNorm: h = out/denom (anchors only) + x.  deg is constant per row ->
// cancels exactly under LN; skipped.  One wave per node, fp32 in/out.
// ---------------------------------------------------------------------------
__global__ __launch_bounds__(256) void ln_k(
    const float* __restrict__ x, const float* __restrict__ out,
    const float* __restrict__ denom, const float* __restrict__ gamma,
    const float* __restrict__ beta, float* __restrict__ y)
{
    int n = blockIdx.x * 4 + (threadIdx.x >> 6);
    if (n >= N_NODES) return;
    int lane = threadIdx.x & 63;
    int ch = lane * 4;
    float4 xv = *(const float4*)(x + (size_t)n * 256 + ch);
    float h0 = xv.x, h1 = xv.y, h2 = xv.z, h3 = xv.w;
    if (n < 256) {
        float den = denom[n * 8 + (lane >> 3)];
        float inv = (den > 0.f) ? 1.0f / den : 0.0f;
        const float* op = out + (size_t)n * 256 + ch;
        h0 += op[0] * inv; h1 += op[1] * inv;
        h2 += op[2] * inv; h3 += op[3] * inv;
    }
    float s = h0 + h1 + h2 + h3;
#pragma unroll
    for (int off = 1; off < 64; off <<= 1) s += __shfl_xor(s, off);
    float mu = s * (1.0f / 256.0f);
    float d0 = h0 - mu, d1 = h1 - mu, d2 = h2 - mu, d3 = h3 - mu;
    float q = d0 * d0 + d1 * d1 + d2 * d2 + d3 * d3;
#pragma unroll
    for (int off = 1; off < 64; off <<= 1) q += __shfl_xor(q, off);
    float rstd = rsqrtf(q * (1.0f / 256.0f) + 1e-5f);
    float4 gv = *(const float4*)(gamma + ch);
    float4 bv = *(const float4*)(beta + ch);
    float4 o;
    o.x = d0 * rstd * gv.x + bv.x;
    o.y = d1 * rstd * gv.y + bv.y;
    o.z = d2 * rstd * gv.z + bv.z;
    o.w = d3 * rstd * gv.w + bv.w;
    *(float4*)(y + (size_t)n * 256 + ch) = o;
}

// ---------------------------------------------------------------------------
extern "C" void kernel_launch(void* const* d_in, const int* in_sizes, int n_in,
                              void* d_out, int out_size, void* d_ws, size_t ws_size,
                              hipStream_t stream)
{
    const float* x     = (const float*)d_in[0];
    const int*   src   = (const int*)d_in[1];
    const int*   dst   = (const int*)d_in[2];
    const float* Wq    = (const float*)d_in[3];
    const float* bq    = (const float*)d_in[4];
    const float* Wk    = (const float*)d_in[5];
    const float* bk    = (const float*)d_in[6];
    const float* Wv    = (const float*)d_in[7];
    const float* bv    = (const float*)d_in[8];
    const float* spd_w = (const float*)d_in[9];
    const float* gamma = (const float*)d_in[10];
    const float* beta  = (const float*)d_in[11];
    float* y = (float*)d_out;

    char* ws = (char*)d_ws;
    // --- zeroed region [0, 278528) ---
    float* denom     = (float*)(ws + 0);          //   8192 B
    float* outf      = (float*)(ws + 8192);       // 262144 B
    u32*   inmask    = (u32*)(ws + 270336);       //   8192 B (zero region ends 278528)
    // --- rest (all written before read) ---
    u32*   dst_off   = (u32*)(ws + 278528);       //   1028 B (pad to 280576)
    unsigned char* T = (unsigned char*)(ws + 280576); // 65536 B
    u32*   blockhist = (u32*)(ws + 346112);       // 262144 B
    u32*   blockbase = (u32*)(ws + 608256);       // 262144 B
    u32*   eidx      = (u32*)(ws + 870400);       // 1.2 MB
    u16*   Qb        = (u16*)(ws + 2070400);      // 128 KB
    u16*   Kb        = (u16*)(ws + 2201472);      // 25.6 MB
    u16*   Vb        = (u16*)(ws + 27801472);     // 25.6 MB
    u16*   Wqb       = (u16*)(ws + 53401472);     // 128 KB
    u16*   Wkb       = (u16*)(ws + 53532544);     // 128 KB
    u16*   Wvb       = (u16*)(ws + 53663616);     // 128 KB (end ~53.8 MB)

    hipMemsetAsync(d_ws, 0, 278528, stream);

    dim3 blk(256);
    cvt_w<<<dim3(192), blk, 0, stream>>>(Wq, Wk, Wv, Wqb, Wkb, Wvb);
    gemm_q<<<dim3(4, 4), blk, 0, stream>>>(x, Wqb, bq, Qb, 256);
    gemm_kv<<<dim3(782, 4), blk, 0, stream>>>(x, Wkb, Wvb, bk, bv, Kb, Vb, N_NODES);
    hist_k<<<dim3(NB_SORT), blk, 0, stream>>>(src, dst, blockhist, inmask);
    off_k<<<dim3(1), blk, 0, stream>>>(blockhist, dst_off, blockbase);
    spd_levels<<<dim3(1), blk, 0, stream>>>(inmask, T);
    scatter2_k<<<dim3(NB_SORT), blk, 0, stream>>>(dst, blockbase, eidx);
    agg_k<<<dim3(256 * 8), blk, 0, stream>>>(src, eidx, dst_off, Qb, Kb, Vb, T, spd_w, outf, denom);
    ln_k<<<dim3((N_NODES + 3) / 4), blk, 0, stream>>>(x, outf, denom, gamma, beta, y);
}